// Round 1
// baseline (2566.989 us; speedup 1.0000x reference)
//
#include <hip/hip_runtime.h>
#include <math.h>

#define B_ 4
#define N_ 1024
#define H_ 1024
#define NH_ 16
#define D_ 64

#define SZ_ATTN (B_*NH_*N_)        // 65536
#define SZ_HEADS (B_*NH_*N_*D_)    // 4194304

// ---------------------------------------------------------------------------
// padd[b] = index of first zero in padding_vector[b,:], or N
// ---------------------------------------------------------------------------
__global__ void padd_kernel(const int* __restrict__ pv, int* __restrict__ padd) {
    __shared__ int mn;
    const int b = blockIdx.x;
    if (threadIdx.x == 0) mn = N_;
    __syncthreads();
    for (int m = threadIdx.x; m < N_; m += blockDim.x)
        if (pv[b*N_ + m] == 0) atomicMin(&mn, m);
    __syncthreads();
    if (threadIdx.x == 0) padd[b] = mn;
}

// ---------------------------------------------------------------------------
// C[i][j] = sum_k X[i,k] * W[j,k] + bias[j], written in heads layout
// out[((b*NH + head)*N + n)*D + dd],  i = b*N+n, j = head*64+dd
// 64x64 tile, 256 threads, 4x4 per thread, fp32.
// ---------------------------------------------------------------------------
__global__ __launch_bounds__(256)
void proj_kernel(const float* __restrict__ X, const float* __restrict__ W,
                 const float* __restrict__ bias, float* __restrict__ outH)
{
    __shared__ float As[16][66];   // [kk][row], pad 66 -> conflict-free
    __shared__ float Bs[16][66];
    const int tid = threadIdx.x;
    const int tx = tid & 15, ty = tid >> 4;
    const int i0 = blockIdx.y * 64;
    const int j0 = blockIdx.x * 64;

    float acc[4][4];
    #pragma unroll
    for (int r = 0; r < 4; ++r)
        #pragma unroll
        for (int c = 0; c < 4; ++c) acc[r][c] = 0.f;

    for (int kt = 0; kt < H_; kt += 16) {
        __syncthreads();
        #pragma unroll
        for (int l = 0; l < 4; ++l) {
            const int e = tid + 256*l;
            const int kk = e & 15, row = e >> 4;
            As[kk][row] = X[(i0+row)*H_ + kt + kk];
            Bs[kk][row] = W[(j0+row)*H_ + kt + kk];
        }
        __syncthreads();
        #pragma unroll
        for (int kk = 0; kk < 16; ++kk) {
            float a[4], b[4];
            #pragma unroll
            for (int r = 0; r < 4; ++r) a[r] = As[kk][ty*4+r];
            #pragma unroll
            for (int c = 0; c < 4; ++c) b[c] = Bs[kk][tx*4+c];
            #pragma unroll
            for (int r = 0; r < 4; ++r)
                #pragma unroll
                for (int c = 0; c < 4; ++c)
                    acc[r][c] += a[r]*b[c];
        }
    }

    const int head = j0 >> 6;   // 64-wide tile aligned to one head
    #pragma unroll
    for (int r = 0; r < 4; ++r) {
        const int i = i0 + ty*4 + r;
        const int bb = i >> 10, n = i & 1023;
        float* dst = outH + ((size_t)(bb*NH_ + head)*N_ + n)*D_;
        #pragma unroll
        for (int c = 0; c < 4; ++c) {
            const int j = j0 + tx*4 + c;
            dst[j & 63] = acc[r][c] + bias[j];
        }
    }
}

// ---------------------------------------------------------------------------
// scores[bh][n][m] = dot(Q[bh][n], K[bh][m]) * 0.125  (raw, unmasked)
// 64x64 output tile per block, K-dim = 64 fully in LDS.
// ---------------------------------------------------------------------------
__global__ __launch_bounds__(256)
void scores_kernel(const float* __restrict__ Q, const float* __restrict__ K,
                   float* __restrict__ S)
{
    __shared__ float Qs[64][66];    // [n_row][kk]
    __shared__ float Kst[64][66];   // [kk][m_row] (transposed)
    const int tid = threadIdx.x;
    const int tx = tid & 15, ty = tid >> 4;
    const int bh = blockIdx.z;
    const int n0 = blockIdx.y * 64, m0 = blockIdx.x * 64;
    const float* Qb = Q + (size_t)bh*N_*D_;
    const float* Kb = K + (size_t)bh*N_*D_;

    #pragma unroll
    for (int l = 0; l < 4; ++l) {
        const int idx = tid + 256*l;
        const int row = idx >> 4, c4 = idx & 15;
        const float4 q4 = *(const float4*)(Qb + (size_t)(n0+row)*D_ + c4*4);
        Qs[row][c4*4+0] = q4.x; Qs[row][c4*4+1] = q4.y;
        Qs[row][c4*4+2] = q4.z; Qs[row][c4*4+3] = q4.w;
        const float4 k4 = *(const float4*)(Kb + (size_t)(m0+row)*D_ + c4*4);
        Kst[c4*4+0][row] = k4.x; Kst[c4*4+1][row] = k4.y;
        Kst[c4*4+2][row] = k4.z; Kst[c4*4+3][row] = k4.w;
    }
    __syncthreads();

    float acc[4][4];
    #pragma unroll
    for (int r = 0; r < 4; ++r)
        #pragma unroll
        for (int c = 0; c < 4; ++c) acc[r][c] = 0.f;

    #pragma unroll 16
    for (int kk = 0; kk < 64; ++kk) {
        float a[4], b[4];
        #pragma unroll
        for (int r = 0; r < 4; ++r) a[r] = Qs[ty*4+r][kk];
        #pragma unroll
        for (int c = 0; c < 4; ++c) b[c] = Kst[kk][tx*4+c];
        #pragma unroll
        for (int r = 0; r < 4; ++r)
            #pragma unroll
            for (int c = 0; c < 4; ++c)
                acc[r][c] += a[r]*b[c];
    }

    float* Sb = S + (size_t)bh*N_*N_;
    #pragma unroll
    for (int r = 0; r < 4; ++r) {
        const int n = n0 + ty*4 + r;
        float4 o;
        o.x = acc[r][0]*0.125f; o.y = acc[r][1]*0.125f;
        o.z = acc[r][2]*0.125f; o.w = acc[r][3]*0.125f;
        *(float4*)(Sb + (size_t)n*N_ + m0 + tx*4) = o;
    }
}

// ---------------------------------------------------------------------------
// Masked softmax over scores rows, context = probs @ V, attention_values =
// column sums of probs. One block handles RPB rows of one (b,h).
// ---------------------------------------------------------------------------
#define RPB 16
__global__ __launch_bounds__(256)
void softmax_ctx_kernel(const float* __restrict__ S, const float* __restrict__ Vh,
                        const int* __restrict__ padd,
                        float* __restrict__ ctx, float* __restrict__ attn)
{
    __shared__ float p[N_];
    __shared__ float colsum[N_];
    __shared__ float rbuf[4];
    __shared__ float bval;
    __shared__ float redc[256];
    const int tid = threadIdx.x;
    const int lane = tid & 63, wid = tid >> 6;
    const int b = blockIdx.z, h = blockIdx.y;
    const int bh = b*NH_ + h;
    const int n0 = blockIdx.x * RPB;
    const int pd = padd[b];

    for (int m = tid; m < N_; m += 256) colsum[m] = 0.f;
    __syncthreads();

    const float* vb = Vh + (size_t)bh*N_*D_;

    for (int r = 0; r < RPB; ++r) {
        const int n = n0 + r;
        float* crow = ctx + ((size_t)bh*N_ + n)*D_;
        if (n >= pd) {              // fully-masked row: probs == 0
            if (tid < D_) crow[tid] = 0.f;
            continue;               // block-uniform, safe
        }
        const float* srow = S + (size_t)bh*N_*N_ + (size_t)n*N_;

        // pass 1: row max over valid cols
        float mx = -INFINITY;
        for (int m = tid; m < pd; m += 256) mx = fmaxf(mx, srow[m]);
        #pragma unroll
        for (int o = 32; o > 0; o >>= 1) mx = fmaxf(mx, __shfl_down(mx, o, 64));
        if (lane == 0) rbuf[wid] = mx;
        __syncthreads();
        if (tid == 0) bval = fmaxf(fmaxf(rbuf[0], rbuf[1]), fmaxf(rbuf[2], rbuf[3]));
        __syncthreads();
        const float smax = bval;

        // pass 2: exp + sum
        float sm = 0.f;
        for (int m = tid; m < pd; m += 256) {
            const float e = __expf(srow[m] - smax);
            p[m] = e;
            sm += e;
        }
        #pragma unroll
        for (int o = 32; o > 0; o >>= 1) sm += __shfl_down(sm, o, 64);
        if (lane == 0) rbuf[wid] = sm;
        __syncthreads();
        if (tid == 0) bval = rbuf[0]+rbuf[1]+rbuf[2]+rbuf[3];
        __syncthreads();
        const float inv = 1.f / bval;

        // normalize + column sums
        for (int m = tid; m < pd; m += 256) {
            const float pr = p[m] * inv;
            p[m] = pr;
            colsum[m] += pr;
        }
        __syncthreads();

        // context row: ctx[n][dd] = sum_m p[m] * V[m][dd]
        const int dd = tid & 63, g = tid >> 6;
        float ca = 0.f;
        for (int m = g; m < pd; m += 4) ca += p[m] * vb[m*D_ + dd];
        redc[tid] = ca;
        __syncthreads();
        if (tid < D_) crow[tid] = redc[tid] + redc[tid+64] + redc[tid+128] + redc[tid+192];
        __syncthreads();
    }

    for (int m = tid; m < pd; m += 256)
        atomicAdd(&attn[(size_t)bh*N_ + m], colsum[m]);
}

// ---------------------------------------------------------------------------
extern "C" void kernel_launch(void* const* d_in, const int* in_sizes, int n_in,
                              void* d_out, int out_size, void* d_ws, size_t ws_size,
                              hipStream_t stream)
{
    const float* hs = (const float*)d_in[0];
    const int*   pv = (const int*)d_in[1];
    const float* Wq = (const float*)d_in[2];
    const float* bq = (const float*)d_in[3];
    const float* Wk = (const float*)d_in[4];
    const float* bk = (const float*)d_in[5];
    const float* Wv = (const float*)d_in[6];
    const float* bv = (const float*)d_in[7];
    float* out = (float*)d_out;

    float* out_attn = out;                       // (B,NH,N)
    float* out_k    = out_attn + SZ_ATTN;        // (B,NH,N,D)
    float* out_q    = out_k + SZ_HEADS;          // (B,NH,N,D)
    float* out_ctx  = out_q + SZ_HEADS;          // (B,NH,N,D)
    float* out_sc   = out_ctx + SZ_HEADS;        // (B,NH,N,N)

    int*   padd = (int*)d_ws;
    float* v_ws = (float*)((char*)d_ws + 256);   // (B,NH,N,D) = 16 MB

    hipMemsetAsync(out_attn, 0, SZ_ATTN*sizeof(float), stream);
    padd_kernel<<<B_, 256, 0, stream>>>(pv, padd);

    dim3 pg(H_/64, (B_*N_)/64);   // (16, 64)
    proj_kernel<<<pg, 256, 0, stream>>>(hs, Wq, bq, out_q);
    proj_kernel<<<pg, 256, 0, stream>>>(hs, Wk, bk, out_k);
    proj_kernel<<<pg, 256, 0, stream>>>(hs, Wv, bv, v_ws);

    dim3 sg(N_/64, N_/64, B_*NH_);  // (16, 16, 64)
    scores_kernel<<<sg, 256, 0, stream>>>(out_q, out_k, out_sc);

    dim3 dg(N_/RPB, NH_, B_);       // (64, 16, 4)
    softmax_ctx_kernel<<<dg, 256, 0, stream>>>(out_sc, v_ws, padd, out_ctx, out_attn);
}

// Round 2
// 1024.256 us; speedup vs baseline: 2.5062x; 2.5062x over previous
//
#include <hip/hip_runtime.h>
#include <math.h>

#define B_ 4
#define N_ 1024
#define H_ 1024
#define NH_ 16
#define D_ 64

#define SZ_ATTN (B_*NH_*N_)        // 65536
#define SZ_HEADS (B_*NH_*N_*D_)    // 4194304

// ---------------------------------------------------------------------------
// padd[b] = index of first zero in padding_vector[b,:], or N
// ---------------------------------------------------------------------------
__global__ void padd_kernel(const int* __restrict__ pv, int* __restrict__ padd) {
    __shared__ int mn;
    const int b = blockIdx.x;
    if (threadIdx.x == 0) mn = N_;
    __syncthreads();
    for (int m = threadIdx.x; m < N_; m += blockDim.x)
        if (pv[b*N_ + m] == 0) atomicMin(&mn, m);
    __syncthreads();
    if (threadIdx.x == 0) padd[b] = mn;
}

// ---------------------------------------------------------------------------
// C[i][j] = sum_k X[i,k] * W[j,k] + bias[j], written in heads layout
// ---------------------------------------------------------------------------
__global__ __launch_bounds__(256)
void proj_kernel(const float* __restrict__ X, const float* __restrict__ W,
                 const float* __restrict__ bias, float* __restrict__ outH)
{
    __shared__ float As[16][66];
    __shared__ float Bs[16][66];
    const int tid = threadIdx.x;
    const int tx = tid & 15, ty = tid >> 4;
    const int i0 = blockIdx.y * 64;
    const int j0 = blockIdx.x * 64;

    float acc[4][4];
    #pragma unroll
    for (int r = 0; r < 4; ++r)
        #pragma unroll
        for (int c = 0; c < 4; ++c) acc[r][c] = 0.f;

    for (int kt = 0; kt < H_; kt += 16) {
        __syncthreads();
        #pragma unroll
        for (int l = 0; l < 4; ++l) {
            const int e = tid + 256*l;
            const int kk = e & 15, row = e >> 4;
            As[kk][row] = X[(i0+row)*H_ + kt + kk];
            Bs[kk][row] = W[(j0+row)*H_ + kt + kk];
        }
        __syncthreads();
        #pragma unroll
        for (int kk = 0; kk < 16; ++kk) {
            float a[4], b[4];
            #pragma unroll
            for (int r = 0; r < 4; ++r) a[r] = As[kk][ty*4+r];
            #pragma unroll
            for (int c = 0; c < 4; ++c) b[c] = Bs[kk][tx*4+c];
            #pragma unroll
            for (int r = 0; r < 4; ++r)
                #pragma unroll
                for (int c = 0; c < 4; ++c)
                    acc[r][c] += a[r]*b[c];
        }
    }

    const int head = j0 >> 6;
    #pragma unroll
    for (int r = 0; r < 4; ++r) {
        const int i = i0 + ty*4 + r;
        const int bb = i >> 10, n = i & 1023;
        float* dst = outH + ((size_t)(bb*NH_ + head)*N_ + n)*D_;
        #pragma unroll
        for (int c = 0; c < 4; ++c) {
            const int j = j0 + tx*4 + c;
            dst[j & 63] = acc[r][c] + bias[j];
        }
    }
}

// ---------------------------------------------------------------------------
// scores[bh][n][m] = dot(Q[bh][n], K[bh][m]) * 0.125  (raw, unmasked)
// ---------------------------------------------------------------------------
__global__ __launch_bounds__(256)
void scores_kernel(const float* __restrict__ Q, const float* __restrict__ K,
                   float* __restrict__ S)
{
    __shared__ float Qs[64][66];
    __shared__ float Kst[64][66];
    const int tid = threadIdx.x;
    const int tx = tid & 15, ty = tid >> 4;
    const int bh = blockIdx.z;
    const int n0 = blockIdx.y * 64, m0 = blockIdx.x * 64;
    const float* Qb = Q + (size_t)bh*N_*D_;
    const float* Kb = K + (size_t)bh*N_*D_;

    #pragma unroll
    for (int l = 0; l < 4; ++l) {
        const int idx = tid + 256*l;
        const int row = idx >> 4, c4 = idx & 15;
        const float4 q4 = *(const float4*)(Qb + (size_t)(n0+row)*D_ + c4*4);
        Qs[row][c4*4+0] = q4.x; Qs[row][c4*4+1] = q4.y;
        Qs[row][c4*4+2] = q4.z; Qs[row][c4*4+3] = q4.w;
        const float4 k4 = *(const float4*)(Kb + (size_t)(m0+row)*D_ + c4*4);
        Kst[c4*4+0][row] = k4.x; Kst[c4*4+1][row] = k4.y;
        Kst[c4*4+2][row] = k4.z; Kst[c4*4+3][row] = k4.w;
    }
    __syncthreads();

    float acc[4][4];
    #pragma unroll
    for (int r = 0; r < 4; ++r)
        #pragma unroll
        for (int c = 0; c < 4; ++c) acc[r][c] = 0.f;

    #pragma unroll 16
    for (int kk = 0; kk < 64; ++kk) {
        float a[4], b[4];
        #pragma unroll
        for (int r = 0; r < 4; ++r) a[r] = Qs[ty*4+r][kk];
        #pragma unroll
        for (int c = 0; c < 4; ++c) b[c] = Kst[kk][tx*4+c];
        #pragma unroll
        for (int r = 0; r < 4; ++r)
            #pragma unroll
            for (int c = 0; c < 4; ++c)
                acc[r][c] += a[r]*b[c];
    }

    float* Sb = S + (size_t)bh*N_*N_;
    #pragma unroll
    for (int r = 0; r < 4; ++r) {
        const int n = n0 + ty*4 + r;
        float4 o;
        o.x = acc[r][0]*0.125f; o.y = acc[r][1]*0.125f;
        o.z = acc[r][2]*0.125f; o.w = acc[r][3]*0.125f;
        *(float4*)(Sb + (size_t)n*N_ + m0 + tx*4) = o;
    }
}

// ---------------------------------------------------------------------------
// rowstats: one wave per score row. Row (1024 floats) loaded into registers
// via 4x float4/lane; masked max + sumexp; write mx and 1/sum per row.
// ---------------------------------------------------------------------------
__global__ __launch_bounds__(256)
void rowstats_kernel(const float* __restrict__ S, const int* __restrict__ padd,
                     float* __restrict__ mx_out, float* __restrict__ inv_out)
{
    const int tid = threadIdx.x;
    const int lane = tid & 63, w = tid >> 6;
    const int row = blockIdx.x * 4 + w;       // global row in [0, B*NH*N)
    const int bh = row >> 10;
    const int n  = row & (N_-1);
    const int b  = bh >> 4;
    const int pd = padd[b];
    if (n >= pd) {
        if (lane == 0) { mx_out[row] = 0.f; inv_out[row] = 0.f; }
        return;
    }
    const float* srow = S + (size_t)row * N_;
    float v[4][4];
    #pragma unroll
    for (int g = 0; g < 4; ++g) {
        const float4 t = *(const float4*)(srow + g*256 + lane*4);
        v[g][0]=t.x; v[g][1]=t.y; v[g][2]=t.z; v[g][3]=t.w;
    }
    float mx = -INFINITY;
    #pragma unroll
    for (int g = 0; g < 4; ++g)
        #pragma unroll
        for (int j = 0; j < 4; ++j) {
            const int m = g*256 + lane*4 + j;
            if (m < pd) mx = fmaxf(mx, v[g][j]);
        }
    #pragma unroll
    for (int o = 32; o > 0; o >>= 1) mx = fmaxf(mx, __shfl_xor(mx, o, 64));
    float sm = 0.f;
    #pragma unroll
    for (int g = 0; g < 4; ++g)
        #pragma unroll
        for (int j = 0; j < 4; ++j) {
            const int m = g*256 + lane*4 + j;
            if (m < pd) sm += __expf(v[g][j] - mx);
        }
    #pragma unroll
    for (int o = 32; o > 0; o >>= 1) sm += __shfl_xor(sm, o, 64);
    if (lane == 0) { mx_out[row] = mx; inv_out[row] = 1.f / sm; }
}

// ---------------------------------------------------------------------------
// probs_ctx: per (bh, 64-row n-tile): iterate over 64-wide m-tiles; compute
// probs on the fly into LDS, accumulate column sums (-> attn via atomics)
// and the 64x64x64 tile-GEMM probs @ V into ctx.
// ---------------------------------------------------------------------------
__global__ __launch_bounds__(256)
void probs_ctx_kernel(const float* __restrict__ S, const float* __restrict__ Vh,
                      const float* __restrict__ mx_in, const float* __restrict__ inv_in,
                      const int* __restrict__ padd,
                      float* __restrict__ ctx, float* __restrict__ attn)
{
    __shared__ float Ps[64][66];
    __shared__ float Vs[64][66];
    __shared__ float smx[64], sinv[64];
    __shared__ float cred[256];
    const int tid = threadIdx.x;
    const int tx = tid & 15, ty = tid >> 4;
    const int bh = blockIdx.y;
    const int n0 = blockIdx.x * 64;
    const int b  = bh >> 4;
    const int pd = padd[b];

    if (n0 >= pd) {   // whole tile of fully-masked rows: ctx = 0 (block-uniform)
        #pragma unroll
        for (int r = 0; r < 4; ++r) {
            const int n = n0 + ty*4 + r;
            float4 z; z.x = z.y = z.z = z.w = 0.f;
            *(float4*)(ctx + ((size_t)bh*N_ + n)*D_ + tx*4) = z;
        }
        return;
    }

    if (tid < 64) {
        smx[tid]  = mx_in[(size_t)bh*N_ + n0 + tid];
        sinv[tid] = inv_in[(size_t)bh*N_ + n0 + tid];
    }
    __syncthreads();

    float acc[4][4];
    #pragma unroll
    for (int r = 0; r < 4; ++r)
        #pragma unroll
        for (int c = 0; c < 4; ++c) acc[r][c] = 0.f;

    for (int m0 = 0; m0 < pd; m0 += 64) {
        // stage probs + V tiles
        #pragma unroll
        for (int l = 0; l < 4; ++l) {
            const int e = tid + 256*l;
            const int row = e >> 4, c4 = e & 15;
            const int n = n0 + row;
            const int m = m0 + c4*4;
            const float4 s4 = *(const float4*)(S + ((size_t)bh*N_ + n)*N_ + m);
            const bool rv = n < pd;
            const float fmx = smx[row], fiv = sinv[row];
            Ps[row][c4*4+0] = (rv && m+0 < pd) ? __expf(s4.x - fmx)*fiv : 0.f;
            Ps[row][c4*4+1] = (rv && m+1 < pd) ? __expf(s4.y - fmx)*fiv : 0.f;
            Ps[row][c4*4+2] = (rv && m+2 < pd) ? __expf(s4.z - fmx)*fiv : 0.f;
            Ps[row][c4*4+3] = (rv && m+3 < pd) ? __expf(s4.w - fmx)*fiv : 0.f;
            const float4 v4 = *(const float4*)(Vh + ((size_t)bh*N_ + m0 + row)*D_ + c4*4);
            Vs[row][c4*4+0] = v4.x; Vs[row][c4*4+1] = v4.y;
            Vs[row][c4*4+2] = v4.z; Vs[row][c4*4+3] = v4.w;
        }
        __syncthreads();

        // column sums of this probs tile -> attention_values
        {
            const int ml = tid & 63, q = tid >> 6;
            float cs = 0.f;
            #pragma unroll
            for (int i = 0; i < 16; ++i) cs += Ps[q*16+i][ml];
            cred[tid] = cs;
        }
        __syncthreads();
        if (tid < 64) {
            const float vtot = cred[tid] + cred[tid+64] + cred[tid+128] + cred[tid+192];
            atomicAdd(&attn[(size_t)bh*N_ + m0 + tid], vtot);
        }

        // tile GEMM: ctx[n][d] += sum_m p[n][m] * V[m][d]
        #pragma unroll 16
        for (int m = 0; m < 64; ++m) {
            float a[4], bb[4];
            #pragma unroll
            for (int r = 0; r < 4; ++r) a[r] = Ps[ty*4+r][m];
            #pragma unroll
            for (int c = 0; c < 4; ++c) bb[c] = Vs[m][tx*4+c];
            #pragma unroll
            for (int r = 0; r < 4; ++r)
                #pragma unroll
                for (int c = 0; c < 4; ++c)
                    acc[r][c] += a[r]*bb[c];
        }
        __syncthreads();   // protect LDS before next tile's staging
    }

    #pragma unroll
    for (int r = 0; r < 4; ++r) {
        const int n = n0 + ty*4 + r;   // rows n>=pd have acc==0 (probs were 0)
        float4 o;
        o.x = acc[r][0]; o.y = acc[r][1]; o.z = acc[r][2]; o.w = acc[r][3];
        *(float4*)(ctx + ((size_t)bh*N_ + n)*D_ + tx*4) = o;
    }
}

// ---------------------------------------------------------------------------
extern "C" void kernel_launch(void* const* d_in, const int* in_sizes, int n_in,
                              void* d_out, int out_size, void* d_ws, size_t ws_size,
                              hipStream_t stream)
{
    const float* hs = (const float*)d_in[0];
    const int*   pv = (const int*)d_in[1];
    const float* Wq = (const float*)d_in[2];
    const float* bq = (const float*)d_in[3];
    const float* Wk = (const float*)d_in[4];
    const float* bk = (const float*)d_in[5];
    const float* Wv = (const float*)d_in[6];
    const float* bv = (const float*)d_in[7];
    float* out = (float*)d_out;

    float* out_attn = out;                       // (B,NH,N)
    float* out_k    = out_attn + SZ_ATTN;        // (B,NH,N,D)
    float* out_q    = out_k + SZ_HEADS;          // (B,NH,N,D)
    float* out_ctx  = out_q + SZ_HEADS;          // (B,NH,N,D)
    float* out_sc   = out_ctx + SZ_HEADS;        // (B,NH,N,N)

    int*   padd = (int*)d_ws;
    float* v_ws = (float*)((char*)d_ws + 256);               // (B,NH,N,D) 16 MB
    float* mx_ws  = v_ws + SZ_HEADS;                          // (B,NH,N) 256 KB
    float* inv_ws = mx_ws + SZ_ATTN;                          // (B,NH,N) 256 KB

    hipMemsetAsync(out_attn, 0, SZ_ATTN*sizeof(float), stream);
    padd_kernel<<<B_, 256, 0, stream>>>(pv, padd);

    dim3 pg(H_/64, (B_*N_)/64);
    proj_kernel<<<pg, 256, 0, stream>>>(hs, Wq, bq, out_q);
    proj_kernel<<<pg, 256, 0, stream>>>(hs, Wk, bk, out_k);
    proj_kernel<<<pg, 256, 0, stream>>>(hs, Wv, bv, v_ws);

    dim3 sg(N_/64, N_/64, B_*NH_);
    scores_kernel<<<sg, 256, 0, stream>>>(out_q, out_k, out_sc);

    rowstats_kernel<<<(B_*NH_*N_)/4, 256, 0, stream>>>(out_sc, padd, mx_ws, inv_ws);

    dim3 cg(N_/64, B_*NH_);
    probs_ctx_kernel<<<cg, 256, 0, stream>>>(out_sc, v_ws, mx_ws, inv_ws, padd,
                                             out_ctx, out_attn);
}